// Round 13
// baseline (303.792 us; speedup 1.0000x reference)
//
#include <hip/hip_runtime.h>

#define DEV static __device__ __forceinline__

typedef __attribute__((ext_vector_type(8))) short short8;
typedef __attribute__((ext_vector_type(4))) float f32x4;

DEV float bf2f(unsigned short u){ union{unsigned i; float f;} a; a.i=((unsigned)u)<<16; return a.f; }
DEV unsigned short f2bf(float f){ union{unsigned i; float f;} a; a.f=f; unsigned r=a.i+0x7fffu+((a.i>>16)&1u); return (unsigned short)(r>>16); }
DEV float2 bfu2f2(unsigned v){ union{unsigned i; float f;} lo,hi; lo.i=v<<16; hi.i=v&0xffff0000u; return make_float2(lo.f,hi.f); }

// Coarse bins: 512 nodes each. Edge packed as src | (dst&511)<<23  (src < 2^23).
#define CB_SHIFT 9
#define CB_NODES 512
#define PK_SHIFT 23
#define PK_MASK  0x7fffffu
#define CHUNK 4096
#define P_WIN 4
#define BIN_CAP 18432

// ---------------- pass 0: coarse histogram (LDS-privatized) ----------------
__global__ __launch_bounds__(256) void coarsehist_kernel(const int* __restrict__ dst,
    int* __restrict__ bcnt, int E, int NB){
  __shared__ int h[256];
  int t=threadIdx.x;
  h[t]=0; __syncthreads();
  int i=blockIdx.x*256+t, st=gridDim.x*256;
  for(;i<E;i+=st) atomicAdd(&h[dst[i]>>CB_SHIFT],1);
  __syncthreads();
  if(t<NB && h[t]) atomicAdd(&bcnt[t],h[t]);
}

// ---------------- bin scan (1 block) ----------------
__global__ __launch_bounds__(256) void binscan_kernel(const int* __restrict__ bcnt,
    int* __restrict__ binoffs, int* __restrict__ bincur, int NB, int E){
  __shared__ int s[256];
  int t=threadIdx.x;
  int v=(t<NB)?bcnt[t]:0;
  s[t]=v; __syncthreads();
  for(int o=1;o<256;o<<=1){
    int u=(t>=o)?s[t-o]:0;
    __syncthreads();
    if(t>=o) s[t]+=u;
    __syncthreads();
  }
  int ex=s[t]-v;
  if(t<NB){ binoffs[t]=ex; bincur[t]=ex; }
  if(t==0) binoffs[NB]=E;
}

// ---------------- pass 1: chunked scatter, LDS bin-sorted for coalesced emission ----------------
__global__ __launch_bounds__(256) void chunkscatter_kernel(const int* __restrict__ src,
    const int* __restrict__ dst, int* __restrict__ bincur, unsigned* __restrict__ tmp,
    int E, int NB){
  __shared__ int lcnt[256];
  __shared__ int lstart[256];
  __shared__ int lbase[256];
  __shared__ unsigned pk[CHUNK];
  __shared__ int gaddr[CHUNK];
  int t=threadIdx.x;
  lcnt[t]=0; __syncthreads();
  int e0=blockIdx.x*CHUNK, e1=min(e0+CHUNK,E);
  int n=e1-e0;
  unsigned pkr[16]; int binr[16]; int rnk[16];
  #pragma unroll
  for(int q=0;q<16;q++){
    int i=e0+t+q*256;
    if(i<e1){
      int d=dst[i];
      int b=d>>CB_SHIFT;
      binr[q]=b;
      pkr[q]=(unsigned)src[i]|((unsigned)(d&(CB_NODES-1))<<PK_SHIFT);
      rnk[q]=atomicAdd(&lcnt[b],1);
    }
  }
  __syncthreads();
  int c=lcnt[t];
  lstart[t]=c; __syncthreads();
  for(int o=1;o<256;o<<=1){
    int u=(t>=o)?lstart[t-o]:0;
    __syncthreads();
    if(t>=o) lstart[t]+=u;
    __syncthreads();
  }
  int ex=lstart[t]-c;
  __syncthreads();
  lstart[t]=ex;
  lbase[t]=(t<NB&&c)?atomicAdd(&bincur[t],c):0;
  __syncthreads();
  #pragma unroll
  for(int q=0;q<16;q++){
    int i=e0+t+q*256;
    if(i<e1){
      int b=binr[q];
      int p=lstart[b]+rnk[q];
      pk[p]=pkr[q];
      gaddr[p]=lbase[b]+rnk[q];
    }
  }
  __syncthreads();
  for(int p=t;p<n;p+=256) tmp[gaddr[p]]=pk[p];
}

// ---------------- pass 2: per-bin (node,window) sort; emits offs/deg/dinv/col ----------------
__global__ __launch_bounds__(512) void binsort_kernel(const unsigned* __restrict__ tmp,
    const int* __restrict__ binoffs, int* __restrict__ offs, int* __restrict__ deg,
    float* __restrict__ dinv, int* __restrict__ col, int M, int WSZ){
  __shared__ int cnt[CB_NODES*P_WIN];
  __shared__ int cur[CB_NODES*P_WIN];
  __shared__ int ssum[512];
  __shared__ int pkl[BIN_CAP];
  int b=blockIdx.x, t=threadIdx.x;
  int n0=b*CB_NODES;
  int e0=binoffs[b], e1=binoffs[b+1];
  int n=e1-e0;
  bool fit=(n<=BIN_CAP);
  cnt[4*t]=0; cnt[4*t+1]=0; cnt[4*t+2]=0; cnt[4*t+3]=0;
  __syncthreads();
  for(int i=e0+t;i<e1;i+=512){
    unsigned p=tmp[i];
    int s=(int)(p&PK_MASK);
    int w=(s>=WSZ)+(s>=2*WSZ)+(s>=3*WSZ);
    atomicAdd(&cnt[(int)(p>>PK_SHIFT)*P_WIN+w],1);
  }
  __syncthreads();
  int loc[4]; int s=0;
  #pragma unroll
  for(int q=0;q<4;q++){ loc[q]=s; s+=cnt[t*4+q]; }
  ssum[t]=s; __syncthreads();
  for(int o=1;o<512;o<<=1){
    int u=(t>=o)?ssum[t-o]:0;
    __syncthreads();
    if(t>=o) ssum[t]+=u;
    __syncthreads();
  }
  int rel=ssum[t]-s;
  #pragma unroll
  for(int q=0;q<4;q++) cur[t*4+q]=rel+loc[q];
  int nn=n0+t;
  if(nn<M){
    offs[nn]=e0+rel; deg[nn]=s; dinv[nn]=rsqrtf((float)(s+1));
  }
  __syncthreads();
  for(int i=e0+t;i<e1;i+=512){
    unsigned p=tmp[i];
    int s2=(int)(p&PK_MASK);
    int w=(s2>=WSZ)+(s2>=2*WSZ)+(s2>=3*WSZ);
    int pos=atomicAdd(&cur[(int)(p>>PK_SHIFT)*P_WIN+w],1);
    if(fit) pkl[pos]=s2;
    else col[e0+pos]=s2;
  }
  __syncthreads();
  if(fit){
    for(int i=t;i<n;i+=512) col[e0+i]=pkl[i];
  }
}

// ---------------- xs0 = dinv * x -> bf16 [M,32] (dims>=21 zero) ----------------
__global__ __launch_bounds__(256) void scale_kernel(const float* __restrict__ x, const float* __restrict__ dinv,
    uint2* __restrict__ xs, int M){
  int idx=blockIdx.x*256+threadIdx.x;
  if(idx>=M*8) return;
  int n=idx>>3, l=idx&7;
  float dv=dinv[n];
  const float* xr=x+(size_t)n*21;
  int c=4*l;
  float f0=(c  <21)?xr[c  ]*dv:0.f;
  float f1=(c+1<21)?xr[c+1]*dv:0.f;
  float f2v=(c+2<21)?xr[c+2]*dv:0.f;
  float f3=(c+3<21)?xr[c+3]*dv:0.f;
  uint2 v;
  v.x=(unsigned)f2bf(f0)|((unsigned)f2bf(f1)<<16);
  v.y=(unsigned)f2bf(f2v)|((unsigned)f2bf(f3)<<16);
  xs[(size_t)n*8+l]=v;
}

// ---------------- aggregation gather core: a0..a3 = row sum over [e0,e0+d) ----------------
// 8/4/1 unroll, low VGPR, high occupancy (R7/R10-proven shape).
template<int GROUP>
DEV void agg_gather(const uint2* __restrict__ xs, const int* __restrict__ col,
    int e0, int d, int lane, float& a0, float& a1, float& a2, float& a3){
  int i=0;
  for(;i+8<=d;i+=8){
    int s[8]; uint2 w[8];
    #pragma unroll
    for(int q=0;q<8;q++) s[q]=col[e0+i+q];
    #pragma unroll
    for(int q=0;q<8;q++) w[q]=xs[(size_t)s[q]*GROUP+lane];
    #pragma unroll
    for(int q=0;q<8;q++){
      float2 p=bfu2f2(w[q].x); a0+=p.x; a1+=p.y;
      p=bfu2f2(w[q].y); a2+=p.x; a3+=p.y;
    }
  }
  for(;i+4<=d;i+=4){
    int s[4]; uint2 w[4];
    #pragma unroll
    for(int q=0;q<4;q++) s[q]=col[e0+i+q];
    #pragma unroll
    for(int q=0;q<4;q++) w[q]=xs[(size_t)s[q]*GROUP+lane];
    #pragma unroll
    for(int q=0;q<4;q++){
      float2 p=bfu2f2(w[q].x); a0+=p.x; a1+=p.y;
      p=bfu2f2(w[q].y); a2+=p.x; a3+=p.y;
    }
  }
  for(;i<d;i++){
    uint2 w=xs[(size_t)col[e0+i]*GROUP+lane];
    float2 p=bfu2f2(w.x); a0+=p.x; a1+=p.y;
    p=bfu2f2(w.y); a2+=p.x; a3+=p.y;
  }
}

// ---------------- agg1/agg2: out = dinv*(self + sum), bf16 out ----------------
template<int GROUP>
DEV void agg_body(const uint2* __restrict__ xs, const int* __restrict__ col,
    const int* __restrict__ offs, const int* __restrict__ deg, const float* __restrict__ dinv,
    uint2* __restrict__ out, int M){
  int gid=blockIdx.x*256+threadIdx.x;
  int node=gid/GROUP, lane=gid%GROUP;
  if(node>=M) return;
  float a0,a1,a2,a3;
  {
    uint2 v=xs[(size_t)node*GROUP+lane];
    float2 p=bfu2f2(v.x), q=bfu2f2(v.y);
    a0=p.x; a1=p.y; a2=q.x; a3=q.y;
  }
  agg_gather<GROUP>(xs,col,offs[node],deg[node],lane,a0,a1,a2,a3);
  float dv=dinv[node];
  a0*=dv; a1*=dv; a2*=dv; a3*=dv;
  uint2 v;
  v.x=(unsigned)f2bf(a0)|((unsigned)f2bf(a1)<<16);
  v.y=(unsigned)f2bf(a2)|((unsigned)f2bf(a3)<<16);
  out[(size_t)node*GROUP+lane]=v;
}

__global__ __launch_bounds__(256) void agg1_kernel(const uint2* xs, const int* col, const int* offs,
    const int* deg, const float* dinv, uint2* out, int M){
  agg_body<8>(xs,col,offs,deg,dinv,out,M);
}
__global__ __launch_bounds__(256) void agg2_kernel(const uint2* xs, const int* col, const int* offs,
    const int* deg, const float* dinv, uint2* out, int M){
  agg_body<16>(xs,col,offs,deg,dinv,out,M);
}

// ---------------- agg3 + fused MLP head: out[n] = MLP(relu(dinv*(self+sum)+b3)) ----------------
// GROUP=16. h3 row staged in padded LDS (stride 68 -> bank-disjoint rows);
// lane l computes hidden unit l (lanes 0..3 also 16+l) -> conflict-free W1s reads
// (consecutive banks within group, broadcast across groups); 4 shfl_xor to reduce.
__global__ __launch_bounds__(256) void agg3mlp_kernel(const uint2* __restrict__ xs, const int* __restrict__ col,
    const int* __restrict__ offs, const int* __restrict__ deg, const float* __restrict__ dinv,
    const float* __restrict__ b3, const float* __restrict__ Wl1, const float* __restrict__ bl1,
    const float* __restrict__ Wl2, const float* __restrict__ bl2, float* __restrict__ out, int M){
  __shared__ float W1s[64*20];
  __shared__ float b1s[20];
  __shared__ float W2s[20];
  __shared__ float b2s;
  __shared__ float hsh[16*68];   // 16 groups x 64 (+4 pad -> rows bank-offset by 4)
  int tid=threadIdx.x;
  for(int i=tid;i<1280;i+=256) W1s[i]=Wl1[i];
  if(tid<20){ b1s[tid]=bl1[tid]; W2s[tid]=Wl2[tid]; }
  if(tid==0) b2s=bl2[0];
  __syncthreads();
  int gid=blockIdx.x*256+tid;
  int node=gid>>4, lane=gid&15;
  int g=tid>>4;
  bool act=(node<M);
  float a0=0.f,a1=0.f,a2=0.f,a3=0.f;
  if(act){
    uint2 v=xs[(size_t)node*16+lane];
    float2 p=bfu2f2(v.x), q=bfu2f2(v.y);
    a0=p.x; a1=p.y; a2=q.x; a3=q.y;
    agg_gather<16>(xs,col,offs[node],deg[node],lane,a0,a1,a2,a3);
    float dv=dinv[node];
    a0=fmaxf(a0*dv+b3[4*lane  ],0.f);
    a1=fmaxf(a1*dv+b3[4*lane+1],0.f);
    a2=fmaxf(a2*dv+b3[4*lane+2],0.f);
    a3=fmaxf(a3*dv+b3[4*lane+3],0.f);
  }
  *(float4*)&hsh[g*68+4*lane]=make_float4(a0,a1,a2,a3);
  __syncthreads();
  // hidden unit `lane` (+ unit 16+lane for lanes 0..3), h broadcast from LDS
  bool has2=(lane<4);
  int u2=16+lane;
  float hid0=0.f, hid1=0.f;
  const float* hr=&hsh[g*68];
  #pragma unroll
  for(int k4=0;k4<16;k4++){
    float4 hv=*(const float4*)&hr[4*k4];
    hid0=fmaf(hv.x,W1s[(4*k4  )*20+lane],hid0);
    hid0=fmaf(hv.y,W1s[(4*k4+1)*20+lane],hid0);
    hid0=fmaf(hv.z,W1s[(4*k4+2)*20+lane],hid0);
    hid0=fmaf(hv.w,W1s[(4*k4+3)*20+lane],hid0);
    if(has2){
      hid1=fmaf(hv.x,W1s[(4*k4  )*20+u2],hid1);
      hid1=fmaf(hv.y,W1s[(4*k4+1)*20+u2],hid1);
      hid1=fmaf(hv.z,W1s[(4*k4+2)*20+u2],hid1);
      hid1=fmaf(hv.w,W1s[(4*k4+3)*20+u2],hid1);
    }
  }
  float c=fmaxf(hid0+b1s[lane],0.f)*W2s[lane];
  if(has2) c+=fmaxf(hid1+b1s[u2],0.f)*W2s[u2];
  c+=__shfl_xor(c,1,16);
  c+=__shfl_xor(c,2,16);
  c+=__shfl_xor(c,4,16);
  c+=__shfl_xor(c,8,16);
  if(act&&lane==0) out[node]=c+b2s;
}

// ---------------- W prep: split f32 W[K][N] (rows>=RK zero) into frag-ready bf16 hi/lo ----------------
__global__ __launch_bounds__(256) void wprep_kernel(const float* __restrict__ W,
    unsigned short* __restrict__ Warr, int KS, int RK, int N, int KN){
  int idx=blockIdx.x*256+threadIdx.x;
  if(idx>=KN) return;
  int j=idx&7, l=(idx>>3)&63, t=idx>>9;
  int ks=t%KS, nt=t/KS;
  int k=ks*32+((l>>4)<<3)+j;
  int c=nt*16+(l&15);
  float w=(k<RK)?W[(size_t)k*N+c]:0.f;
  unsigned short hi=f2bf(w);
  unsigned short lo=f2bf(w-bf2f(hi));
  Warr[idx]=hi;
  Warr[KN+idx]=lo;
}

// ---------------- MFMA GEMM (no LDS): Out[M,N]=epi(Xbf16[M,K] @ (Whi+Wlo)) ----------------
template<int K,int NT,bool BR,bool DV>
DEV void mfma_gemm_body(const unsigned short* __restrict__ X, const unsigned short* __restrict__ Warr,
    const float* __restrict__ bias, const float* __restrict__ dinv, unsigned short* __restrict__ Out, int M){
  constexpr int KS=K/32;
  constexpr int N=NT*16;
  constexpr int KN=K*N;
  int tid=threadIdx.x;
  int lane=tid&63, wave=tid>>6;
  int rowbase=blockIdx.x*64+wave*16;
  int r=rowbase+(lane&15);
  int rc=min(r,M-1);
  const short* Xr=(const short*)(X+(size_t)rc*K+((lane>>4)<<3));
  short8 af[KS];
  #pragma unroll
  for(int ks=0;ks<KS;ks++) af[ks]=*(const short8*)(Xr+ks*32);
  const short* wp=(const short*)Warr+lane*8;
  int colv=lane&15;
  #pragma unroll
  for(int nt=0;nt<NT;nt++){
    f32x4 acc={0.f,0.f,0.f,0.f};
    const short* wnt=wp+nt*KS*512;
    #pragma unroll
    for(int ks=0;ks<KS;ks++){
      short8 bh=*(const short8*)(wnt+ks*512);
      short8 bl=*(const short8*)(wnt+KN+ks*512);
      acc=__builtin_amdgcn_mfma_f32_16x16x32_bf16(af[ks],bh,acc,0,0,0);
      acc=__builtin_amdgcn_mfma_f32_16x16x32_bf16(af[ks],bl,acc,0,0,0);
    }
    int c=nt*16+colv;
    float bv=0.f;
    if constexpr(BR) bv=bias[c];
    #pragma unroll
    for(int reg=0;reg<4;reg++){
      int row=rowbase+((lane>>4)<<2)+reg;
      if(row<M){
        float v=acc[reg];
        if constexpr(BR) v=fmaxf(v+bv,0.f);
        if constexpr(DV) v*=dinv[row];
        Out[(size_t)row*N+c]=f2bf(v);
      }
    }
  }
}

__global__ __launch_bounds__(256) void gemm1m_kernel(const unsigned short* X, const unsigned short* Warr,
    const float* bias, const float* dinv, unsigned short* Out, int M){
  mfma_gemm_body<32,4,true,true>(X,Warr,bias,dinv,Out,M);
}

// ---------------- fused GEMM2+GEMM3: ts = dinv*( relu(Y2@W2+b2) @ W3 ), h2 stays in LDS ----------------
__global__ __launch_bounds__(256) void gemm23_kernel(const unsigned short* __restrict__ X,
    const unsigned short* __restrict__ W2arr, const unsigned short* __restrict__ W3arr,
    const float* __restrict__ bias2, const float* __restrict__ dinv,
    unsigned short* __restrict__ Out, int M){
  __shared__ unsigned short h2t[4*16*128];
  int tid=threadIdx.x, lane=tid&63, wave=tid>>6;
  int rowbase=blockIdx.x*64+wave*16;
  unsigned short* base=h2t+wave*16*128;
  {
    int r=rowbase+(lane&15);
    int rc=min(r,M-1);
    const short* Xr=(const short*)(X+(size_t)rc*64+((lane>>4)<<3));
    short8 af0=*(const short8*)(Xr);
    short8 af1=*(const short8*)(Xr+32);
    const short* wp=(const short*)W2arr+lane*8;
    int colv=lane&15;
    #pragma unroll
    for(int nt=0;nt<8;nt++){
      f32x4 acc={0.f,0.f,0.f,0.f};
      const short* wnt=wp+nt*1024;
      short8 bh0=*(const short8*)(wnt);
      short8 bl0=*(const short8*)(wnt+8192);
      short8 bh1=*(const short8*)(wnt+512);
      short8 bl1=*(const short8*)(wnt+8704);
      acc=__builtin_amdgcn_mfma_f32_16x16x32_bf16(af0,bh0,acc,0,0,0);
      acc=__builtin_amdgcn_mfma_f32_16x16x32_bf16(af0,bl0,acc,0,0,0);
      acc=__builtin_amdgcn_mfma_f32_16x16x32_bf16(af1,bh1,acc,0,0,0);
      acc=__builtin_amdgcn_mfma_f32_16x16x32_bf16(af1,bl1,acc,0,0,0);
      int c=nt*16+colv;
      float bv=bias2[c];
      #pragma unroll
      for(int reg=0;reg<4;reg++){
        int wr=((lane>>4)<<2)+reg;
        float v=fmaxf(acc[reg]+bv,0.f);
        int e=wr*128+(((((c>>3)^(wr&7)))<<3)|(c&7));
        base[e]=f2bf(v);
      }
    }
  }
  __syncthreads();
  {
    int wr=lane&15;
    short8 af[4];
    #pragma unroll
    for(int ks=0;ks<4;ks++){
      int chunk=ks*4+(lane>>4);
      int e=wr*128+((chunk^(wr&7))<<3);
      af[ks]=*(const short8*)(base+e);
    }
    const short* wp=(const short*)W3arr+lane*8;
    int colv=lane&15;
    #pragma unroll
    for(int nt=0;nt<4;nt++){
      f32x4 acc={0.f,0.f,0.f,0.f};
      const short* wnt=wp+nt*2048;
      #pragma unroll
      for(int ks=0;ks<4;ks++){
        short8 bh=*(const short8*)(wnt+ks*512);
        short8 bl=*(const short8*)(wnt+8192+ks*512);
        acc=__builtin_amdgcn_mfma_f32_16x16x32_bf16(af[ks],bh,acc,0,0,0);
        acc=__builtin_amdgcn_mfma_f32_16x16x32_bf16(af[ks],bl,acc,0,0,0);
      }
      int c=nt*16+colv;
      #pragma unroll
      for(int reg=0;reg<4;reg++){
        int row=rowbase+((lane>>4)<<2)+reg;
        if(row<M){
          Out[(size_t)row*64+c]=f2bf(acc[reg]*dinv[row]);
        }
      }
    }
  }
}

extern "C" void kernel_launch(void* const* d_in, const int* in_sizes, int n_in,
                              void* d_out, int out_size, void* d_ws, size_t ws_size,
                              hipStream_t stream){
  const float* x  =(const float*)d_in[0];
  const int*   ei =(const int*)  d_in[1];
  const float* W1 =(const float*)d_in[2];
  const float* b1 =(const float*)d_in[3];
  const float* W2 =(const float*)d_in[4];
  const float* b2 =(const float*)d_in[5];
  const float* W3 =(const float*)d_in[6];
  const float* b3 =(const float*)d_in[7];
  const float* Wl1=(const float*)d_in[8];
  const float* bl1=(const float*)d_in[9];
  const float* Wl2=(const float*)d_in[10];
  const float* bl2=(const float*)d_in[11];
  const int M=in_sizes[0]/21;
  const int E=in_sizes[1]/2;
  const int* srcp=ei;
  const int* dstp=ei+(size_t)E;
  const int NB=(M+CB_NODES-1)/CB_NODES;   // coarse bins (<=256 for M<=131072)
  const int WSZ=(M+P_WIN-1)/P_WIN;        // src-window size

  char* ws=(char*)d_ws;
  size_t off=0;
  auto alloc=[&](size_t bytes)->void*{
    off=(off+255)&~(size_t)255;
    void* p=ws+off; off+=bytes; return p;
  };
  int*   offs   =(int*)  alloc((size_t)M*4);
  int*   deg    =(int*)  alloc((size_t)M*4);
  float* dinv   =(float*)alloc((size_t)M*4);
  int*   bcnt   =(int*)  alloc(256*4);
  int*   binoffs=(int*)  alloc(257*4);
  int*   bincur =(int*)  alloc(256*4);
  unsigned short* W1arr=(unsigned short*)alloc(2*32*64*2);    // hi+lo
  unsigned short* W2arr=(unsigned short*)alloc(2*64*128*2);   // hi+lo
  unsigned short* W3arr=(unsigned short*)alloc(2*128*64*2);   // hi+lo
  int*   col    =(int*)  alloc((size_t)E*4);
  // reusable 256B-per-node slots
  float* A=(float*)alloc((size_t)M*256);   // (alias: uint tmp[E]) xs0 bf16[M,32]
  float* B=(float*)alloc((size_t)M*256);   // Y1 bf16[M,32] -> ts bf16[M,64]
  float* C=(float*)alloc((size_t)M*256);   // xs1 bf16[M,64]
  float* D=(float*)alloc((size_t)M*256);   // Y2 bf16[M,64]
  unsigned* tmp=(unsigned*)A;              // E*4 bytes <= M*256 bytes
  (void)ws_size;(void)n_in;(void)out_size;

  hipMemsetAsync(bcnt,0,256*4,stream);
  coarsehist_kernel<<<512,256,0,stream>>>(dstp,bcnt,E,NB);
  binscan_kernel<<<1,256,0,stream>>>(bcnt,binoffs,bincur,NB,E);
  chunkscatter_kernel<<<(E+CHUNK-1)/CHUNK,256,0,stream>>>(srcp,dstp,bincur,tmp,E,NB);
  binsort_kernel<<<NB,512,0,stream>>>(tmp,binoffs,offs,deg,dinv,col,M,WSZ);
  wprep_kernel<<<(32*64+255)/256,256,0,stream>>>(W1,W1arr,1,21,64,32*64);
  wprep_kernel<<<(64*128+255)/256,256,0,stream>>>(W2,W2arr,2,64,128,64*128);
  wprep_kernel<<<(128*64+255)/256,256,0,stream>>>(W3,W3arr,4,128,64,128*64);

  // layer 1: xs0 bf16[M,32]; aggregate (GROUP=8, out bf16 Y1); MFMA GEMM 21->64 (bias+relu+dinv, bf16 xs1)
  scale_kernel<<<(M*8+255)/256,256,0,stream>>>(x,dinv,(uint2*)A,M);
  agg1_kernel<<<(M*8+255)/256,256,0,stream>>>((const uint2*)A,col,offs,deg,dinv,(uint2*)B,M);
  gemm1m_kernel<<<(M+63)/64,256,0,stream>>>((const unsigned short*)B,W1arr,b1,dinv,(unsigned short*)C,M);
  // layer 2+3 GEMMs fused: aggregate (GROUP=16, out bf16 Y2); Y2 -> (h2 in LDS) -> ts bf16
  agg2_kernel<<<(M*16+255)/256,256,0,stream>>>((const uint2*)C,col,offs,deg,dinv,(uint2*)D,M);
  gemm23_kernel<<<(M+63)/64,256,0,stream>>>((const unsigned short*)D,W2arr,W3arr,b2,dinv,(unsigned short*)B,M);
  // layer 3 aggregate + fused MLP head -> d_out
  agg3mlp_kernel<<<(M*16+255)/256,256,0,stream>>>((const uint2*)B,col,offs,deg,dinv,b3,
      Wl1,bl1,Wl2,bl2,(float*)d_out,M);
}

// Round 14
// 269.803 us; speedup vs baseline: 1.1260x; 1.1260x over previous
//
#include <hip/hip_runtime.h>

#define DEV static __device__ __forceinline__

typedef __attribute__((ext_vector_type(8))) short short8;
typedef __attribute__((ext_vector_type(4))) float f32x4;

DEV float bf2f(unsigned short u){ union{unsigned i; float f;} a; a.i=((unsigned)u)<<16; return a.f; }
DEV unsigned short f2bf(float f){ union{unsigned i; float f;} a; a.f=f; unsigned r=a.i+0x7fffu+((a.i>>16)&1u); return (unsigned short)(r>>16); }
DEV float2 bfu2f2(unsigned v){ union{unsigned i; float f;} lo,hi; lo.i=v<<16; hi.i=v&0xffff0000u; return make_float2(lo.f,hi.f); }

// Coarse bins: 512 nodes each. Edge packed as src | (dst&511)<<23  (src < 2^23).
#define CB_SHIFT 9
#define CB_NODES 512
#define PK_SHIFT 23
#define PK_MASK  0x7fffffu
#define CHUNK 4096
#define P_WIN 4
#define BIN_CAP 18432

// ---------------- pass 0: coarse histogram (LDS-privatized) ----------------
__global__ __launch_bounds__(256) void coarsehist_kernel(const int* __restrict__ dst,
    int* __restrict__ bcnt, int E, int NB){
  __shared__ int h[256];
  int t=threadIdx.x;
  h[t]=0; __syncthreads();
  int i=blockIdx.x*256+t, st=gridDim.x*256;
  for(;i<E;i+=st) atomicAdd(&h[dst[i]>>CB_SHIFT],1);
  __syncthreads();
  if(t<NB && h[t]) atomicAdd(&bcnt[t],h[t]);
}

// ---------------- bin scan (1 block) ----------------
__global__ __launch_bounds__(256) void binscan_kernel(const int* __restrict__ bcnt,
    int* __restrict__ binoffs, int* __restrict__ bincur, int NB, int E){
  __shared__ int s[256];
  int t=threadIdx.x;
  int v=(t<NB)?bcnt[t]:0;
  s[t]=v; __syncthreads();
  for(int o=1;o<256;o<<=1){
    int u=(t>=o)?s[t-o]:0;
    __syncthreads();
    if(t>=o) s[t]+=u;
    __syncthreads();
  }
  int ex=s[t]-v;
  if(t<NB){ binoffs[t]=ex; bincur[t]=ex; }
  if(t==0) binoffs[NB]=E;
}

// ---------------- pass 1: chunked scatter, LDS bin-sorted for coalesced emission ----------------
__global__ __launch_bounds__(256) void chunkscatter_kernel(const int* __restrict__ src,
    const int* __restrict__ dst, int* __restrict__ bincur, unsigned* __restrict__ tmp,
    int E, int NB){
  __shared__ int lcnt[256];
  __shared__ int lstart[256];
  __shared__ int lbase[256];
  __shared__ unsigned pk[CHUNK];
  __shared__ int gaddr[CHUNK];
  int t=threadIdx.x;
  lcnt[t]=0; __syncthreads();
  int e0=blockIdx.x*CHUNK, e1=min(e0+CHUNK,E);
  int n=e1-e0;
  unsigned pkr[16]; int binr[16]; int rnk[16];
  #pragma unroll
  for(int q=0;q<16;q++){
    int i=e0+t+q*256;
    if(i<e1){
      int d=dst[i];
      int b=d>>CB_SHIFT;
      binr[q]=b;
      pkr[q]=(unsigned)src[i]|((unsigned)(d&(CB_NODES-1))<<PK_SHIFT);
      rnk[q]=atomicAdd(&lcnt[b],1);
    }
  }
  __syncthreads();
  int c=lcnt[t];
  lstart[t]=c; __syncthreads();
  for(int o=1;o<256;o<<=1){
    int u=(t>=o)?lstart[t-o]:0;
    __syncthreads();
    if(t>=o) lstart[t]+=u;
    __syncthreads();
  }
  int ex=lstart[t]-c;
  __syncthreads();
  lstart[t]=ex;
  lbase[t]=(t<NB&&c)?atomicAdd(&bincur[t],c):0;
  __syncthreads();
  #pragma unroll
  for(int q=0;q<16;q++){
    int i=e0+t+q*256;
    if(i<e1){
      int b=binr[q];
      int p=lstart[b]+rnk[q];
      pk[p]=pkr[q];
      gaddr[p]=lbase[b]+rnk[q];
    }
  }
  __syncthreads();
  for(int p=t;p<n;p+=256) tmp[gaddr[p]]=pk[p];
}

// ---------------- pass 2: per-bin (node,window) sort; emits offs/deg/dinv/col ----------------
__global__ __launch_bounds__(512) void binsort_kernel(const unsigned* __restrict__ tmp,
    const int* __restrict__ binoffs, int* __restrict__ offs, int* __restrict__ deg,
    float* __restrict__ dinv, int* __restrict__ col, int M, int WSZ){
  __shared__ int cnt[CB_NODES*P_WIN];
  __shared__ int cur[CB_NODES*P_WIN];
  __shared__ int ssum[512];
  __shared__ int pkl[BIN_CAP];
  int b=blockIdx.x, t=threadIdx.x;
  int n0=b*CB_NODES;
  int e0=binoffs[b], e1=binoffs[b+1];
  int n=e1-e0;
  bool fit=(n<=BIN_CAP);
  cnt[4*t]=0; cnt[4*t+1]=0; cnt[4*t+2]=0; cnt[4*t+3]=0;
  __syncthreads();
  for(int i=e0+t;i<e1;i+=512){
    unsigned p=tmp[i];
    int s=(int)(p&PK_MASK);
    int w=(s>=WSZ)+(s>=2*WSZ)+(s>=3*WSZ);
    atomicAdd(&cnt[(int)(p>>PK_SHIFT)*P_WIN+w],1);
  }
  __syncthreads();
  int loc[4]; int s=0;
  #pragma unroll
  for(int q=0;q<4;q++){ loc[q]=s; s+=cnt[t*4+q]; }
  ssum[t]=s; __syncthreads();
  for(int o=1;o<512;o<<=1){
    int u=(t>=o)?ssum[t-o]:0;
    __syncthreads();
    if(t>=o) ssum[t]+=u;
    __syncthreads();
  }
  int rel=ssum[t]-s;
  #pragma unroll
  for(int q=0;q<4;q++) cur[t*4+q]=rel+loc[q];
  int nn=n0+t;
  if(nn<M){
    offs[nn]=e0+rel; deg[nn]=s; dinv[nn]=rsqrtf((float)(s+1));
  }
  __syncthreads();
  for(int i=e0+t;i<e1;i+=512){
    unsigned p=tmp[i];
    int s2=(int)(p&PK_MASK);
    int w=(s2>=WSZ)+(s2>=2*WSZ)+(s2>=3*WSZ);
    int pos=atomicAdd(&cur[(int)(p>>PK_SHIFT)*P_WIN+w],1);
    if(fit) pkl[pos]=s2;
    else col[e0+pos]=s2;
  }
  __syncthreads();
  if(fit){
    for(int i=t;i<n;i+=512) col[e0+i]=pkl[i];
  }
}

// ---------------- xs0 = dinv * x -> bf16 [M,32] (dims>=21 zero) ----------------
__global__ __launch_bounds__(256) void scale_kernel(const float* __restrict__ x, const float* __restrict__ dinv,
    uint2* __restrict__ xs, int M){
  int idx=blockIdx.x*256+threadIdx.x;
  if(idx>=M*8) return;
  int n=idx>>3, l=idx&7;
  float dv=dinv[n];
  const float* xr=x+(size_t)n*21;
  int c=4*l;
  float f0=(c  <21)?xr[c  ]*dv:0.f;
  float f1=(c+1<21)?xr[c+1]*dv:0.f;
  float f2v=(c+2<21)?xr[c+2]*dv:0.f;
  float f3=(c+3<21)?xr[c+3]*dv:0.f;
  uint2 v;
  v.x=(unsigned)f2bf(f0)|((unsigned)f2bf(f1)<<16);
  v.y=(unsigned)f2bf(f2v)|((unsigned)f2bf(f3)<<16);
  xs[(size_t)n*8+l]=v;
}

// ---------------- aggregation gather core: a0..a3 = row sum over [e0,e0+d) ----------------
// 8/4/1 unroll, low VGPR, high occupancy (R7/R10-proven shape).
template<int GROUP>
DEV void agg_gather(const uint2* __restrict__ xs, const int* __restrict__ col,
    int e0, int d, int lane, float& a0, float& a1, float& a2, float& a3){
  int i=0;
  for(;i+8<=d;i+=8){
    int s[8]; uint2 w[8];
    #pragma unroll
    for(int q=0;q<8;q++) s[q]=col[e0+i+q];
    #pragma unroll
    for(int q=0;q<8;q++) w[q]=xs[(size_t)s[q]*GROUP+lane];
    #pragma unroll
    for(int q=0;q<8;q++){
      float2 p=bfu2f2(w[q].x); a0+=p.x; a1+=p.y;
      p=bfu2f2(w[q].y); a2+=p.x; a3+=p.y;
    }
  }
  for(;i+4<=d;i+=4){
    int s[4]; uint2 w[4];
    #pragma unroll
    for(int q=0;q<4;q++) s[q]=col[e0+i+q];
    #pragma unroll
    for(int q=0;q<4;q++) w[q]=xs[(size_t)s[q]*GROUP+lane];
    #pragma unroll
    for(int q=0;q<4;q++){
      float2 p=bfu2f2(w[q].x); a0+=p.x; a1+=p.y;
      p=bfu2f2(w[q].y); a2+=p.x; a3+=p.y;
    }
  }
  for(;i<d;i++){
    uint2 w=xs[(size_t)col[e0+i]*GROUP+lane];
    float2 p=bfu2f2(w.x); a0+=p.x; a1+=p.y;
    p=bfu2f2(w.y); a2+=p.x; a3+=p.y;
  }
}

// ---------------- agg: out = [bias+relu](dinv*(self + sum)), bf16 out ----------------
template<int GROUP,bool BR>
DEV void agg_body(const uint2* __restrict__ xs, const int* __restrict__ col,
    const int* __restrict__ offs, const int* __restrict__ deg, const float* __restrict__ dinv,
    const float* __restrict__ bias, uint2* __restrict__ out, int M){
  int gid=blockIdx.x*256+threadIdx.x;
  int node=gid/GROUP, lane=gid%GROUP;
  if(node>=M) return;
  float a0,a1,a2,a3;
  {
    uint2 v=xs[(size_t)node*GROUP+lane];
    float2 p=bfu2f2(v.x), q=bfu2f2(v.y);
    a0=p.x; a1=p.y; a2=q.x; a3=q.y;
  }
  agg_gather<GROUP>(xs,col,offs[node],deg[node],lane,a0,a1,a2,a3);
  float dv=dinv[node];
  a0*=dv; a1*=dv; a2*=dv; a3*=dv;
  if constexpr(BR){
    a0=fmaxf(a0+bias[4*lane  ],0.f);
    a1=fmaxf(a1+bias[4*lane+1],0.f);
    a2=fmaxf(a2+bias[4*lane+2],0.f);
    a3=fmaxf(a3+bias[4*lane+3],0.f);
  }
  uint2 v;
  v.x=(unsigned)f2bf(a0)|((unsigned)f2bf(a1)<<16);
  v.y=(unsigned)f2bf(a2)|((unsigned)f2bf(a3)<<16);
  out[(size_t)node*GROUP+lane]=v;
}

__global__ __launch_bounds__(256) void agg1_kernel(const uint2* xs, const int* col, const int* offs,
    const int* deg, const float* dinv, uint2* out, int M){
  agg_body<8,false>(xs,col,offs,deg,dinv,nullptr,out,M);
}
__global__ __launch_bounds__(256) void agg2_kernel(const uint2* xs, const int* col, const int* offs,
    const int* deg, const float* dinv, uint2* out, int M){
  agg_body<16,false>(xs,col,offs,deg,dinv,nullptr,out,M);
}
__global__ __launch_bounds__(256) void agg3_kernel(const uint2* xs, const int* col, const int* offs,
    const int* deg, const float* dinv, const float* bias, uint2* out, int M){
  agg_body<16,true>(xs,col,offs,deg,dinv,bias,out,M);
}

// ---------------- W prep: split f32 W[K][N] (rows>=RK zero) into frag-ready bf16 hi/lo ----------------
__global__ __launch_bounds__(256) void wprep_kernel(const float* __restrict__ W,
    unsigned short* __restrict__ Warr, int KS, int RK, int N, int KN){
  int idx=blockIdx.x*256+threadIdx.x;
  if(idx>=KN) return;
  int j=idx&7, l=(idx>>3)&63, t=idx>>9;
  int ks=t%KS, nt=t/KS;
  int k=ks*32+((l>>4)<<3)+j;
  int c=nt*16+(l&15);
  float w=(k<RK)?W[(size_t)k*N+c]:0.f;
  unsigned short hi=f2bf(w);
  unsigned short lo=f2bf(w-bf2f(hi));
  Warr[idx]=hi;
  Warr[KN+idx]=lo;
}

// ---------------- MFMA GEMM (no LDS): Out[M,N]=epi(Xbf16[M,K] @ (Whi+Wlo)) ----------------
template<int K,int NT,bool BR,bool DV>
DEV void mfma_gemm_body(const unsigned short* __restrict__ X, const unsigned short* __restrict__ Warr,
    const float* __restrict__ bias, const float* __restrict__ dinv, unsigned short* __restrict__ Out, int M){
  constexpr int KS=K/32;
  constexpr int N=NT*16;
  constexpr int KN=K*N;
  int tid=threadIdx.x;
  int lane=tid&63, wave=tid>>6;
  int rowbase=blockIdx.x*64+wave*16;
  int r=rowbase+(lane&15);
  int rc=min(r,M-1);
  const short* Xr=(const short*)(X+(size_t)rc*K+((lane>>4)<<3));
  short8 af[KS];
  #pragma unroll
  for(int ks=0;ks<KS;ks++) af[ks]=*(const short8*)(Xr+ks*32);
  const short* wp=(const short*)Warr+lane*8;
  int colv=lane&15;
  #pragma unroll
  for(int nt=0;nt<NT;nt++){
    f32x4 acc={0.f,0.f,0.f,0.f};
    const short* wnt=wp+nt*KS*512;
    #pragma unroll
    for(int ks=0;ks<KS;ks++){
      short8 bh=*(const short8*)(wnt+ks*512);
      short8 bl=*(const short8*)(wnt+KN+ks*512);
      acc=__builtin_amdgcn_mfma_f32_16x16x32_bf16(af[ks],bh,acc,0,0,0);
      acc=__builtin_amdgcn_mfma_f32_16x16x32_bf16(af[ks],bl,acc,0,0,0);
    }
    int c=nt*16+colv;
    float bv=0.f;
    if constexpr(BR) bv=bias[c];
    #pragma unroll
    for(int reg=0;reg<4;reg++){
      int row=rowbase+((lane>>4)<<2)+reg;
      if(row<M){
        float v=acc[reg];
        if constexpr(BR) v=fmaxf(v+bv,0.f);
        if constexpr(DV) v*=dinv[row];
        Out[(size_t)row*N+c]=f2bf(v);
      }
    }
  }
}

__global__ __launch_bounds__(256) void gemm1m_kernel(const unsigned short* X, const unsigned short* Warr,
    const float* bias, const float* dinv, unsigned short* Out, int M){
  mfma_gemm_body<32,4,true,true>(X,Warr,bias,dinv,Out,M);
}

// ---------------- fused GEMM2+GEMM3: ts = dinv*( relu(Y2@W2+b2) @ W3 ), h2 stays in LDS ----------------
__global__ __launch_bounds__(256) void gemm23_kernel(const unsigned short* __restrict__ X,
    const unsigned short* __restrict__ W2arr, const unsigned short* __restrict__ W3arr,
    const float* __restrict__ bias2, const float* __restrict__ dinv,
    unsigned short* __restrict__ Out, int M){
  __shared__ unsigned short h2t[4*16*128];
  int tid=threadIdx.x, lane=tid&63, wave=tid>>6;
  int rowbase=blockIdx.x*64+wave*16;
  unsigned short* base=h2t+wave*16*128;
  {
    int r=rowbase+(lane&15);
    int rc=min(r,M-1);
    const short* Xr=(const short*)(X+(size_t)rc*64+((lane>>4)<<3));
    short8 af0=*(const short8*)(Xr);
    short8 af1=*(const short8*)(Xr+32);
    const short* wp=(const short*)W2arr+lane*8;
    int colv=lane&15;
    #pragma unroll
    for(int nt=0;nt<8;nt++){
      f32x4 acc={0.f,0.f,0.f,0.f};
      const short* wnt=wp+nt*1024;
      short8 bh0=*(const short8*)(wnt);
      short8 bl0=*(const short8*)(wnt+8192);
      short8 bh1=*(const short8*)(wnt+512);
      short8 bl1=*(const short8*)(wnt+8704);
      acc=__builtin_amdgcn_mfma_f32_16x16x32_bf16(af0,bh0,acc,0,0,0);
      acc=__builtin_amdgcn_mfma_f32_16x16x32_bf16(af0,bl0,acc,0,0,0);
      acc=__builtin_amdgcn_mfma_f32_16x16x32_bf16(af1,bh1,acc,0,0,0);
      acc=__builtin_amdgcn_mfma_f32_16x16x32_bf16(af1,bl1,acc,0,0,0);
      int c=nt*16+colv;
      float bv=bias2[c];
      #pragma unroll
      for(int reg=0;reg<4;reg++){
        int wr=((lane>>4)<<2)+reg;
        float v=fmaxf(acc[reg]+bv,0.f);
        int e=wr*128+(((((c>>3)^(wr&7)))<<3)|(c&7));
        base[e]=f2bf(v);
      }
    }
  }
  __syncthreads();
  {
    int wr=lane&15;
    short8 af[4];
    #pragma unroll
    for(int ks=0;ks<4;ks++){
      int chunk=ks*4+(lane>>4);
      int e=wr*128+((chunk^(wr&7))<<3);
      af[ks]=*(const short8*)(base+e);
    }
    const short* wp=(const short*)W3arr+lane*8;
    int colv=lane&15;
    #pragma unroll
    for(int nt=0;nt<4;nt++){
      f32x4 acc={0.f,0.f,0.f,0.f};
      const short* wnt=wp+nt*2048;
      #pragma unroll
      for(int ks=0;ks<4;ks++){
        short8 bh=*(const short8*)(wnt+ks*512);
        short8 bl=*(const short8*)(wnt+8192+ks*512);
        acc=__builtin_amdgcn_mfma_f32_16x16x32_bf16(af[ks],bh,acc,0,0,0);
        acc=__builtin_amdgcn_mfma_f32_16x16x32_bf16(af[ks],bl,acc,0,0,0);
      }
      int c=nt*16+colv;
      #pragma unroll
      for(int reg=0;reg<4;reg++){
        int row=rowbase+((lane>>4)<<2)+reg;
        if(row<M){
          Out[(size_t)row*64+c]=f2bf(acc[reg]*dinv[row]);
        }
      }
    }
  }
}

// ---------------- fused MLP head (bf16 input): out = (relu(h@Wl1+bl1))@Wl2 + bl2 ----------------
__global__ __launch_bounds__(256) void mlp_kernel(const unsigned short* __restrict__ h, const float* __restrict__ W1,
    const float* __restrict__ b1, const float* __restrict__ W2, const float* __restrict__ b2,
    float* __restrict__ out, int M){
  __shared__ float W1s[64*20];
  __shared__ float b1s[20];
  __shared__ float W2s[20];
  __shared__ float b2s;
  int tid=threadIdx.x;
  for(int i=tid;i<1280;i+=256) W1s[i]=W1[i];
  if(tid<20){ b1s[tid]=b1[tid]; W2s[tid]=W2[tid]; }
  if(tid==0) b2s=b2[0];
  __syncthreads();
  int n=blockIdx.x*256+tid;
  if(n>=M) return;
  float acc[20];
  #pragma unroll
  for(int j=0;j<20;j++) acc[j]=b1s[j];
  const uint2* hp=(const uint2*)(h+(size_t)n*64);
  for(int k4=0;k4<16;k4++){
    uint2 v=hp[k4];
    float2 p=bfu2f2(v.x), q=bfu2f2(v.y);
    #pragma unroll
    for(int j=0;j<20;j++){
      acc[j]=fmaf(p.x,W1s[(k4*4+0)*20+j],acc[j]);
      acc[j]=fmaf(p.y,W1s[(k4*4+1)*20+j],acc[j]);
      acc[j]=fmaf(q.x,W1s[(k4*4+2)*20+j],acc[j]);
      acc[j]=fmaf(q.y,W1s[(k4*4+3)*20+j],acc[j]);
    }
  }
  float r=b2s;
  #pragma unroll
  for(int j=0;j<20;j++) r+=fmaxf(acc[j],0.f)*W2s[j];
  out[n]=r;
}

extern "C" void kernel_launch(void* const* d_in, const int* in_sizes, int n_in,
                              void* d_out, int out_size, void* d_ws, size_t ws_size,
                              hipStream_t stream){
  const float* x  =(const float*)d_in[0];
  const int*   ei =(const int*)  d_in[1];
  const float* W1 =(const float*)d_in[2];
  const float* b1 =(const float*)d_in[3];
  const float* W2 =(const float*)d_in[4];
  const float* b2 =(const float*)d_in[5];
  const float* W3 =(const float*)d_in[6];
  const float* b3 =(const float*)d_in[7];
  const float* Wl1=(const float*)d_in[8];
  const float* bl1=(const float*)d_in[9];
  const float* Wl2=(const float*)d_in[10];
  const float* bl2=(const float*)d_in[11];
  const int M=in_sizes[0]/21;
  const int E=in_sizes[1]/2;
  const int* srcp=ei;
  const int* dstp=ei+(size_t)E;
  const int NB=(M+CB_NODES-1)/CB_NODES;   // coarse bins (<=256 for M<=131072)
  const int WSZ=(M+P_WIN-1)/P_WIN;        // src-window size

  char* ws=(char*)d_ws;
  size_t off=0;
  auto alloc=[&](size_t bytes)->void*{
    off=(off+255)&~(size_t)255;
    void* p=ws+off; off+=bytes; return p;
  };
  int*   offs   =(int*)  alloc((size_t)M*4);
  int*   deg    =(int*)  alloc((size_t)M*4);
  float* dinv   =(float*)alloc((size_t)M*4);
  int*   bcnt   =(int*)  alloc(256*4);
  int*   binoffs=(int*)  alloc(257*4);
  int*   bincur =(int*)  alloc(256*4);
  unsigned short* W1arr=(unsigned short*)alloc(2*32*64*2);    // hi+lo
  unsigned short* W2arr=(unsigned short*)alloc(2*64*128*2);   // hi+lo
  unsigned short* W3arr=(unsigned short*)alloc(2*128*64*2);   // hi+lo
  int*   col    =(int*)  alloc((size_t)E*4);
  // reusable 256B-per-node slots
  float* A=(float*)alloc((size_t)M*256);   // (alias: uint tmp[E]) xs0 bf16[M,32]
  float* B=(float*)alloc((size_t)M*256);   // Y1 bf16[M,32] -> ts bf16[M,64]
  float* C=(float*)alloc((size_t)M*256);   // xs1 bf16[M,64] -> h3 bf16[M,64]
  float* D=(float*)alloc((size_t)M*256);   // Y2 bf16[M,64]
  unsigned* tmp=(unsigned*)A;              // E*4 bytes <= M*256 bytes
  (void)ws_size;(void)n_in;(void)out_size;

  hipMemsetAsync(bcnt,0,256*4,stream);
  coarsehist_kernel<<<512,256,0,stream>>>(dstp,bcnt,E,NB);
  binscan_kernel<<<1,256,0,stream>>>(bcnt,binoffs,bincur,NB,E);
  chunkscatter_kernel<<<(E+CHUNK-1)/CHUNK,256,0,stream>>>(srcp,dstp,bincur,tmp,E,NB);
  binsort_kernel<<<NB,512,0,stream>>>(tmp,binoffs,offs,deg,dinv,col,M,WSZ);
  wprep_kernel<<<(32*64+255)/256,256,0,stream>>>(W1,W1arr,1,21,64,32*64);
  wprep_kernel<<<(64*128+255)/256,256,0,stream>>>(W2,W2arr,2,64,128,64*128);
  wprep_kernel<<<(128*64+255)/256,256,0,stream>>>(W3,W3arr,4,128,64,128*64);

  // layer 1: xs0 bf16[M,32]; aggregate (GROUP=8, out bf16 Y1); MFMA GEMM 21->64 (bias+relu+dinv, bf16 xs1)
  scale_kernel<<<(M*8+255)/256,256,0,stream>>>(x,dinv,(uint2*)A,M);
  agg1_kernel<<<(M*8+255)/256,256,0,stream>>>((const uint2*)A,col,offs,deg,dinv,(uint2*)B,M);
  gemm1m_kernel<<<(M+63)/64,256,0,stream>>>((const unsigned short*)B,W1arr,b1,dinv,(unsigned short*)C,M);
  // layer 2+3 GEMMs fused: aggregate (GROUP=16, out bf16 Y2); Y2 -> (h2 in LDS) -> ts bf16
  agg2_kernel<<<(M*16+255)/256,256,0,stream>>>((const uint2*)C,col,offs,deg,dinv,(uint2*)D,M);
  gemm23_kernel<<<(M+63)/64,256,0,stream>>>((const unsigned short*)D,W2arr,W3arr,b2,dinv,(unsigned short*)B,M);
  // layer 3 aggregate (bias+relu, bf16 h3)
  agg3_kernel<<<(M*16+255)/256,256,0,stream>>>((const uint2*)B,col,offs,deg,dinv,b3,(uint2*)C,M);
  // MLP head (bf16 input)
  mlp_kernel<<<(M+255)/256,256,0,stream>>>((const unsigned short*)C,Wl1,bl1,Wl2,bl2,(float*)d_out,M);
}

// Round 15
// 266.886 us; speedup vs baseline: 1.1383x; 1.0109x over previous
//
#include <hip/hip_runtime.h>

#define DEV static __device__ __forceinline__

typedef __attribute__((ext_vector_type(8))) short short8;
typedef __attribute__((ext_vector_type(4))) float f32x4;

DEV float bf2f(unsigned short u){ union{unsigned i; float f;} a; a.i=((unsigned)u)<<16; return a.f; }
DEV unsigned short f2bf(float f){ union{unsigned i; float f;} a; a.f=f; unsigned r=a.i+0x7fffu+((a.i>>16)&1u); return (unsigned short)(r>>16); }
DEV float2 bfu2f2(unsigned v){ union{unsigned i; float f;} lo,hi; lo.i=v<<16; hi.i=v&0xffff0000u; return make_float2(lo.f,hi.f); }

// Coarse bins: 512 nodes each. Edge packed as src | (dst&511)<<23  (src < 2^23).
#define CB_SHIFT 9
#define CB_NODES 512
#define PK_SHIFT 23
#define PK_MASK  0x7fffffu
#define CHUNK 4096
#define P_WIN 4
#define BIN_CAP 18432

// ---------------- pass 0: coarse histogram (LDS-privatized) ----------------
__global__ __launch_bounds__(256) void coarsehist_kernel(const int* __restrict__ dst,
    int* __restrict__ bcnt, int E, int NB){
  __shared__ int h[256];
  int t=threadIdx.x;
  h[t]=0; __syncthreads();
  int i=blockIdx.x*256+t, st=gridDim.x*256;
  for(;i<E;i+=st) atomicAdd(&h[dst[i]>>CB_SHIFT],1);
  __syncthreads();
  if(t<NB && h[t]) atomicAdd(&bcnt[t],h[t]);
}

// ---------------- bin scan (1 block) ----------------
__global__ __launch_bounds__(256) void binscan_kernel(const int* __restrict__ bcnt,
    int* __restrict__ binoffs, int* __restrict__ bincur, int NB, int E){
  __shared__ int s[256];
  int t=threadIdx.x;
  int v=(t<NB)?bcnt[t]:0;
  s[t]=v; __syncthreads();
  for(int o=1;o<256;o<<=1){
    int u=(t>=o)?s[t-o]:0;
    __syncthreads();
    if(t>=o) s[t]+=u;
    __syncthreads();
  }
  int ex=s[t]-v;
  if(t<NB){ binoffs[t]=ex; bincur[t]=ex; }
  if(t==0) binoffs[NB]=E;
}

// ---------------- pass 1: chunked scatter, LDS bin-sorted for coalesced emission ----------------
__global__ __launch_bounds__(256) void chunkscatter_kernel(const int* __restrict__ src,
    const int* __restrict__ dst, int* __restrict__ bincur, unsigned* __restrict__ tmp,
    int E, int NB){
  __shared__ int lcnt[256];
  __shared__ int lstart[256];
  __shared__ int lbase[256];
  __shared__ unsigned pk[CHUNK];
  __shared__ int gaddr[CHUNK];
  int t=threadIdx.x;
  lcnt[t]=0; __syncthreads();
  int e0=blockIdx.x*CHUNK, e1=min(e0+CHUNK,E);
  int n=e1-e0;
  unsigned pkr[16]; int binr[16]; int rnk[16];
  #pragma unroll
  for(int q=0;q<16;q++){
    int i=e0+t+q*256;
    if(i<e1){
      int d=dst[i];
      int b=d>>CB_SHIFT;
      binr[q]=b;
      pkr[q]=(unsigned)src[i]|((unsigned)(d&(CB_NODES-1))<<PK_SHIFT);
      rnk[q]=atomicAdd(&lcnt[b],1);
    }
  }
  __syncthreads();
  int c=lcnt[t];
  lstart[t]=c; __syncthreads();
  for(int o=1;o<256;o<<=1){
    int u=(t>=o)?lstart[t-o]:0;
    __syncthreads();
    if(t>=o) lstart[t]+=u;
    __syncthreads();
  }
  int ex=lstart[t]-c;
  __syncthreads();
  lstart[t]=ex;
  lbase[t]=(t<NB&&c)?atomicAdd(&bincur[t],c):0;
  __syncthreads();
  #pragma unroll
  for(int q=0;q<16;q++){
    int i=e0+t+q*256;
    if(i<e1){
      int b=binr[q];
      int p=lstart[b]+rnk[q];
      pk[p]=pkr[q];
      gaddr[p]=lbase[b]+rnk[q];
    }
  }
  __syncthreads();
  for(int p=t;p<n;p+=256) tmp[gaddr[p]]=pk[p];
}

// ---------------- pass 2: per-bin (node,window) sort; emits offs/deg/dinv/col ----------------
__global__ __launch_bounds__(512) void binsort_kernel(const unsigned* __restrict__ tmp,
    const int* __restrict__ binoffs, int* __restrict__ offs, int* __restrict__ deg,
    float* __restrict__ dinv, int* __restrict__ col, int M, int WSZ){
  __shared__ int cnt[CB_NODES*P_WIN];
  __shared__ int cur[CB_NODES*P_WIN];
  __shared__ int ssum[512];
  __shared__ int pkl[BIN_CAP];
  int b=blockIdx.x, t=threadIdx.x;
  int n0=b*CB_NODES;
  int e0=binoffs[b], e1=binoffs[b+1];
  int n=e1-e0;
  bool fit=(n<=BIN_CAP);
  cnt[4*t]=0; cnt[4*t+1]=0; cnt[4*t+2]=0; cnt[4*t+3]=0;
  __syncthreads();
  for(int i=e0+t;i<e1;i+=512){
    unsigned p=tmp[i];
    int s=(int)(p&PK_MASK);
    int w=(s>=WSZ)+(s>=2*WSZ)+(s>=3*WSZ);
    atomicAdd(&cnt[(int)(p>>PK_SHIFT)*P_WIN+w],1);
  }
  __syncthreads();
  int loc[4]; int s=0;
  #pragma unroll
  for(int q=0;q<4;q++){ loc[q]=s; s+=cnt[t*4+q]; }
  ssum[t]=s; __syncthreads();
  for(int o=1;o<512;o<<=1){
    int u=(t>=o)?ssum[t-o]:0;
    __syncthreads();
    if(t>=o) ssum[t]+=u;
    __syncthreads();
  }
  int rel=ssum[t]-s;
  #pragma unroll
  for(int q=0;q<4;q++) cur[t*4+q]=rel+loc[q];
  int nn=n0+t;
  if(nn<M){
    offs[nn]=e0+rel; deg[nn]=s; dinv[nn]=rsqrtf((float)(s+1));
  }
  __syncthreads();
  for(int i=e0+t;i<e1;i+=512){
    unsigned p=tmp[i];
    int s2=(int)(p&PK_MASK);
    int w=(s2>=WSZ)+(s2>=2*WSZ)+(s2>=3*WSZ);
    int pos=atomicAdd(&cur[(int)(p>>PK_SHIFT)*P_WIN+w],1);
    if(fit) pkl[pos]=s2;
    else col[e0+pos]=s2;
  }
  __syncthreads();
  if(fit){
    for(int i=t;i<n;i+=512) col[e0+i]=pkl[i];
  }
}

// ---------------- xs0 = dinv * x -> bf16 [M,32] (dims>=21 zero) ----------------
__global__ __launch_bounds__(256) void scale_kernel(const float* __restrict__ x, const float* __restrict__ dinv,
    uint2* __restrict__ xs, int M){
  int idx=blockIdx.x*256+threadIdx.x;
  if(idx>=M*8) return;
  int n=idx>>3, l=idx&7;
  float dv=dinv[n];
  const float* xr=x+(size_t)n*21;
  int c=4*l;
  float f0=(c  <21)?xr[c  ]*dv:0.f;
  float f1=(c+1<21)?xr[c+1]*dv:0.f;
  float f2v=(c+2<21)?xr[c+2]*dv:0.f;
  float f3=(c+3<21)?xr[c+3]*dv:0.f;
  uint2 v;
  v.x=(unsigned)f2bf(f0)|((unsigned)f2bf(f1)<<16);
  v.y=(unsigned)f2bf(f2v)|((unsigned)f2bf(f3)<<16);
  xs[(size_t)n*8+l]=v;
}

// ---------------- agg gather (32-dim rows, GROUP=8 x uint2) ----------------
DEV void agg_gather32(const uint2* __restrict__ xs, const int* __restrict__ col,
    int e0, int d, int lane, float& a0, float& a1, float& a2, float& a3){
  int i=0;
  for(;i+8<=d;i+=8){
    int s[8]; uint2 w[8];
    #pragma unroll
    for(int q=0;q<8;q++) s[q]=col[e0+i+q];
    #pragma unroll
    for(int q=0;q<8;q++) w[q]=xs[(size_t)s[q]*8+lane];
    #pragma unroll
    for(int q=0;q<8;q++){
      float2 p=bfu2f2(w[q].x); a0+=p.x; a1+=p.y;
      p=bfu2f2(w[q].y); a2+=p.x; a3+=p.y;
    }
  }
  for(;i+4<=d;i+=4){
    int s[4]; uint2 w[4];
    #pragma unroll
    for(int q=0;q<4;q++) s[q]=col[e0+i+q];
    #pragma unroll
    for(int q=0;q<4;q++) w[q]=xs[(size_t)s[q]*8+lane];
    #pragma unroll
    for(int q=0;q<4;q++){
      float2 p=bfu2f2(w[q].x); a0+=p.x; a1+=p.y;
      p=bfu2f2(w[q].y); a2+=p.x; a3+=p.y;
    }
  }
  for(;i<d;i++){
    uint2 w=xs[(size_t)col[e0+i]*8+lane];
    float2 p=bfu2f2(w.x); a0+=p.x; a1+=p.y;
    p=bfu2f2(w.y); a2+=p.x; a3+=p.y;
  }
}

// ---------------- agg1: 32-dim rows, out = dinv*(self+sum), bf16 ----------------
__global__ __launch_bounds__(256) void agg1_kernel(const uint2* __restrict__ xs, const int* __restrict__ col,
    const int* __restrict__ offs, const int* __restrict__ deg, const float* __restrict__ dinv,
    uint2* __restrict__ out, int M){
  int gid=blockIdx.x*256+threadIdx.x;
  int node=gid>>3, lane=gid&7;
  if(node>=M) return;
  float a0,a1,a2,a3;
  {
    uint2 v=xs[(size_t)node*8+lane];
    float2 p=bfu2f2(v.x), q=bfu2f2(v.y);
    a0=p.x; a1=p.y; a2=q.x; a3=q.y;
  }
  agg_gather32(xs,col,offs[node],deg[node],lane,a0,a1,a2,a3);
  float dv=dinv[node];
  a0*=dv; a1*=dv; a2*=dv; a3*=dv;
  uint2 v;
  v.x=(unsigned)f2bf(a0)|((unsigned)f2bf(a1)<<16);
  v.y=(unsigned)f2bf(a2)|((unsigned)f2bf(a3)<<16);
  out[(size_t)node*8+lane]=v;
}

// ---------------- agg64: 64-dim rows, GROUP=8 x uint4 (16B/lane, 2x lines in flight) ----------------
template<bool BR>
DEV void agg64_body(const uint4* __restrict__ xs, const int* __restrict__ col,
    const int* __restrict__ offs, const int* __restrict__ deg, const float* __restrict__ dinv,
    const float* __restrict__ bias, uint4* __restrict__ out, int M){
  int gid=blockIdx.x*256+threadIdx.x;
  int node=gid>>3, lane=gid&7;
  if(node>=M) return;
  float a0,a1,a2,a3,a4,a5,a6,a7;
  {
    uint4 v=xs[(size_t)node*8+lane];
    float2 p=bfu2f2(v.x); a0=p.x; a1=p.y;
    p=bfu2f2(v.y); a2=p.x; a3=p.y;
    p=bfu2f2(v.z); a4=p.x; a5=p.y;
    p=bfu2f2(v.w); a6=p.x; a7=p.y;
  }
  int e0=offs[node], d=deg[node];
  int i=0;
  for(;i+8<=d;i+=8){
    int s[8]; uint4 w[8];
    #pragma unroll
    for(int q=0;q<8;q++) s[q]=col[e0+i+q];
    #pragma unroll
    for(int q=0;q<8;q++) w[q]=xs[(size_t)s[q]*8+lane];
    #pragma unroll
    for(int q=0;q<8;q++){
      float2 p=bfu2f2(w[q].x); a0+=p.x; a1+=p.y;
      p=bfu2f2(w[q].y); a2+=p.x; a3+=p.y;
      p=bfu2f2(w[q].z); a4+=p.x; a5+=p.y;
      p=bfu2f2(w[q].w); a6+=p.x; a7+=p.y;
    }
  }
  for(;i+4<=d;i+=4){
    int s[4]; uint4 w[4];
    #pragma unroll
    for(int q=0;q<4;q++) s[q]=col[e0+i+q];
    #pragma unroll
    for(int q=0;q<4;q++) w[q]=xs[(size_t)s[q]*8+lane];
    #pragma unroll
    for(int q=0;q<4;q++){
      float2 p=bfu2f2(w[q].x); a0+=p.x; a1+=p.y;
      p=bfu2f2(w[q].y); a2+=p.x; a3+=p.y;
      p=bfu2f2(w[q].z); a4+=p.x; a5+=p.y;
      p=bfu2f2(w[q].w); a6+=p.x; a7+=p.y;
    }
  }
  for(;i<d;i++){
    uint4 w=xs[(size_t)col[e0+i]*8+lane];
    float2 p=bfu2f2(w.x); a0+=p.x; a1+=p.y;
    p=bfu2f2(w.y); a2+=p.x; a3+=p.y;
    p=bfu2f2(w.z); a4+=p.x; a5+=p.y;
    p=bfu2f2(w.w); a6+=p.x; a7+=p.y;
  }
  float dv=dinv[node];
  a0*=dv; a1*=dv; a2*=dv; a3*=dv; a4*=dv; a5*=dv; a6*=dv; a7*=dv;
  if constexpr(BR){
    const float* bp=bias+8*lane;
    a0=fmaxf(a0+bp[0],0.f); a1=fmaxf(a1+bp[1],0.f);
    a2=fmaxf(a2+bp[2],0.f); a3=fmaxf(a3+bp[3],0.f);
    a4=fmaxf(a4+bp[4],0.f); a5=fmaxf(a5+bp[5],0.f);
    a6=fmaxf(a6+bp[6],0.f); a7=fmaxf(a7+bp[7],0.f);
  }
  uint4 v;
  v.x=(unsigned)f2bf(a0)|((unsigned)f2bf(a1)<<16);
  v.y=(unsigned)f2bf(a2)|((unsigned)f2bf(a3)<<16);
  v.z=(unsigned)f2bf(a4)|((unsigned)f2bf(a5)<<16);
  v.w=(unsigned)f2bf(a6)|((unsigned)f2bf(a7)<<16);
  out[(size_t)node*8+lane]=v;
}

__global__ __launch_bounds__(256) void agg2_kernel(const uint4* xs, const int* col, const int* offs,
    const int* deg, const float* dinv, uint4* out, int M){
  agg64_body<false>(xs,col,offs,deg,dinv,nullptr,out,M);
}
__global__ __launch_bounds__(256) void agg3_kernel(const uint4* xs, const int* col, const int* offs,
    const int* deg, const float* dinv, const float* bias, uint4* out, int M){
  agg64_body<true>(xs,col,offs,deg,dinv,bias,out,M);
}

// ---------------- W prep: split f32 W[K][N] (rows>=RK zero) into frag-ready bf16 hi/lo ----------------
__global__ __launch_bounds__(256) void wprep_kernel(const float* __restrict__ W,
    unsigned short* __restrict__ Warr, int KS, int RK, int N, int KN){
  int idx=blockIdx.x*256+threadIdx.x;
  if(idx>=KN) return;
  int j=idx&7, l=(idx>>3)&63, t=idx>>9;
  int ks=t%KS, nt=t/KS;
  int k=ks*32+((l>>4)<<3)+j;
  int c=nt*16+(l&15);
  float w=(k<RK)?W[(size_t)k*N+c]:0.f;
  unsigned short hi=f2bf(w);
  unsigned short lo=f2bf(w-bf2f(hi));
  Warr[idx]=hi;
  Warr[KN+idx]=lo;
}

// ---------------- MFMA GEMM (no LDS): Out[M,N]=epi(Xbf16[M,K] @ (Whi+Wlo)) ----------------
template<int K,int NT,bool BR,bool DV>
DEV void mfma_gemm_body(const unsigned short* __restrict__ X, const unsigned short* __restrict__ Warr,
    const float* __restrict__ bias, const float* __restrict__ dinv, unsigned short* __restrict__ Out, int M){
  constexpr int KS=K/32;
  constexpr int N=NT*16;
  constexpr int KN=K*N;
  int tid=threadIdx.x;
  int lane=tid&63, wave=tid>>6;
  int rowbase=blockIdx.x*64+wave*16;
  int r=rowbase+(lane&15);
  int rc=min(r,M-1);
  const short* Xr=(const short*)(X+(size_t)rc*K+((lane>>4)<<3));
  short8 af[KS];
  #pragma unroll
  for(int ks=0;ks<KS;ks++) af[ks]=*(const short8*)(Xr+ks*32);
  const short* wp=(const short*)Warr+lane*8;
  int colv=lane&15;
  #pragma unroll
  for(int nt=0;nt<NT;nt++){
    f32x4 acc={0.f,0.f,0.f,0.f};
    const short* wnt=wp+nt*KS*512;
    #pragma unroll
    for(int ks=0;ks<KS;ks++){
      short8 bh=*(const short8*)(wnt+ks*512);
      short8 bl=*(const short8*)(wnt+KN+ks*512);
      acc=__builtin_amdgcn_mfma_f32_16x16x32_bf16(af[ks],bh,acc,0,0,0);
      acc=__builtin_amdgcn_mfma_f32_16x16x32_bf16(af[ks],bl,acc,0,0,0);
    }
    int c=nt*16+colv;
    float bv=0.f;
    if constexpr(BR) bv=bias[c];
    #pragma unroll
    for(int reg=0;reg<4;reg++){
      int row=rowbase+((lane>>4)<<2)+reg;
      if(row<M){
        float v=acc[reg];
        if constexpr(BR) v=fmaxf(v+bv,0.f);
        if constexpr(DV) v*=dinv[row];
        Out[(size_t)row*N+c]=f2bf(v);
      }
    }
  }
}

__global__ __launch_bounds__(256) void gemm1m_kernel(const unsigned short* X, const unsigned short* Warr,
    const float* bias, const float* dinv, unsigned short* Out, int M){
  mfma_gemm_body<32,4,true,true>(X,Warr,bias,dinv,Out,M);
}

// ---------------- fused GEMM2+GEMM3: ts = dinv*( relu(Y2@W2+b2) @ W3 ), h2 stays in LDS ----------------
__global__ __launch_bounds__(256) void gemm23_kernel(const unsigned short* __restrict__ X,
    const unsigned short* __restrict__ W2arr, const unsigned short* __restrict__ W3arr,
    const float* __restrict__ bias2, const float* __restrict__ dinv,
    unsigned short* __restrict__ Out, int M){
  __shared__ unsigned short h2t[4*16*128];
  int tid=threadIdx.x, lane=tid&63, wave=tid>>6;
  int rowbase=blockIdx.x*64+wave*16;
  unsigned short* base=h2t+wave*16*128;
  {
    int r=rowbase+(lane&15);
    int rc=min(r,M-1);
    const short* Xr=(const short*)(X+(size_t)rc*64+((lane>>4)<<3));
    short8 af0=*(const short8*)(Xr);
    short8 af1=*(const short8*)(Xr+32);
    const short* wp=(const short*)W2arr+lane*8;
    int colv=lane&15;
    #pragma unroll
    for(int nt=0;nt<8;nt++){
      f32x4 acc={0.f,0.f,0.f,0.f};
      const short* wnt=wp+nt*1024;
      short8 bh0=*(const short8*)(wnt);
      short8 bl0=*(const short8*)(wnt+8192);
      short8 bh1=*(const short8*)(wnt+512);
      short8 bl1=*(const short8*)(wnt+8704);
      acc=__builtin_amdgcn_mfma_f32_16x16x32_bf16(af0,bh0,acc,0,0,0);
      acc=__builtin_amdgcn_mfma_f32_16x16x32_bf16(af0,bl0,acc,0,0,0);
      acc=__builtin_amdgcn_mfma_f32_16x16x32_bf16(af1,bh1,acc,0,0,0);
      acc=__builtin_amdgcn_mfma_f32_16x16x32_bf16(af1,bl1,acc,0,0,0);
      int c=nt*16+colv;
      float bv=bias2[c];
      #pragma unroll
      for(int reg=0;reg<4;reg++){
        int wr=((lane>>4)<<2)+reg;
        float v=fmaxf(acc[reg]+bv,0.f);
        int e=wr*128+(((((c>>3)^(wr&7)))<<3)|(c&7));
        base[e]=f2bf(v);
      }
    }
  }
  __syncthreads();
  {
    int wr=lane&15;
    short8 af[4];
    #pragma unroll
    for(int ks=0;ks<4;ks++){
      int chunk=ks*4+(lane>>4);
      int e=wr*128+((chunk^(wr&7))<<3);
      af[ks]=*(const short8*)(base+e);
    }
    const short* wp=(const short*)W3arr+lane*8;
    int colv=lane&15;
    #pragma unroll
    for(int nt=0;nt<4;nt++){
      f32x4 acc={0.f,0.f,0.f,0.f};
      const short* wnt=wp+nt*2048;
      #pragma unroll
      for(int ks=0;ks<4;ks++){
        short8 bh=*(const short8*)(wnt+ks*512);
        short8 bl=*(const short8*)(wnt+8192+ks*512);
        acc=__builtin_amdgcn_mfma_f32_16x16x32_bf16(af[ks],bh,acc,0,0,0);
        acc=__builtin_amdgcn_mfma_f32_16x16x32_bf16(af[ks],bl,acc,0,0,0);
      }
      int c=nt*16+colv;
      #pragma unroll
      for(int reg=0;reg<4;reg++){
        int row=rowbase+((lane>>4)<<2)+reg;
        if(row<M){
          Out[(size_t)row*64+c]=f2bf(acc[reg]*dinv[row]);
        }
      }
    }
  }
}

// ---------------- fused MLP head (bf16 input): out = (relu(h@Wl1+bl1))@Wl2 + bl2 ----------------
__global__ __launch_bounds__(256) void mlp_kernel(const unsigned short* __restrict__ h, const float* __restrict__ W1,
    const float* __restrict__ b1, const float* __restrict__ W2, const float* __restrict__ b2,
    float* __restrict__ out, int M){
  __shared__ float W1s[64*20];
  __shared__ float b1s[20];
  __shared__ float W2s[20];
  __shared__ float b2s;
  int tid=threadIdx.x;
  for(int i=tid;i<1280;i+=256) W1s[i]=W1[i];
  if(tid<20){ b1s[tid]=b1[tid]; W2s[tid]=W2[tid]; }
  if(tid==0) b2s=b2[0];
  __syncthreads();
  int n=blockIdx.x*256+tid;
  if(n>=M) return;
  float acc[20];
  #pragma unroll
  for(int j=0;j<20;j++) acc[j]=b1s[j];
  const uint2* hp=(const uint2*)(h+(size_t)n*64);
  for(int k4=0;k4<16;k4++){
    uint2 v=hp[k4];
    float2 p=bfu2f2(v.x), q=bfu2f2(v.y);
    #pragma unroll
    for(int j=0;j<20;j++){
      acc[j]=fmaf(p.x,W1s[(k4*4+0)*20+j],acc[j]);
      acc[j]=fmaf(p.y,W1s[(k4*4+1)*20+j],acc[j]);
      acc[j]=fmaf(q.x,W1s[(k4*4+2)*20+j],acc[j]);
      acc[j]=fmaf(q.y,W1s[(k4*4+3)*20+j],acc[j]);
    }
  }
  float r=b2s;
  #pragma unroll
  for(int j=0;j<20;j++) r+=fmaxf(acc[j],0.f)*W2s[j];
  out[n]=r;
}

extern "C" void kernel_launch(void* const* d_in, const int* in_sizes, int n_in,
                              void* d_out, int out_size, void* d_ws, size_t ws_size,
                              hipStream_t stream){
  const float* x  =(const float*)d_in[0];
  const int*   ei =(const int*)  d_in[1];
  const float* W1 =(const float*)d_in[2];
  const float* b1 =(const float*)d_in[3];
  const float* W2 =(const float*)d_in[4];
  const float* b2 =(const float*)d_in[5];
  const float* W3 =(const float*)d_in[6];
  const float* b3 =(const float*)d_in[7];
  const float* Wl1=(const float*)d_in[8];
  const float* bl1=(const float*)d_in[9];
  const float* Wl2=(const float*)d_in[10];
  const float* bl2=(const float*)d_in[11];
  const int M=in_sizes[0]/21;
  const int E=in_sizes[1]/2;
  const int* srcp=ei;
  const int* dstp=ei+(size_t)E;
  const int NB=(M+CB_NODES-1)/CB_NODES;   // coarse bins (<=256 for M<=131072)
  const int WSZ=(M+P_WIN-1)/P_WIN;        // src-window size

  char* ws=(char*)d_ws;
  size_t off=0;
  auto alloc=[&](size_t bytes)->void*{
    off=(off+255)&~(size_t)255;
    void* p=ws+off; off+=bytes; return p;
  };
  int*   offs   =(int*)  alloc((size_t)M*4);
  int*   deg    =(int*)  alloc((size_t)M*4);
  float* dinv   =(float*)alloc((size_t)M*4);
  int*   bcnt   =(int*)  alloc(256*4);
  int*   binoffs=(int*)  alloc(257*4);
  int*   bincur =(int*)  alloc(256*4);
  unsigned short* W1arr=(unsigned short*)alloc(2*32*64*2);    // hi+lo
  unsigned short* W2arr=(unsigned short*)alloc(2*64*128*2);   // hi+lo
  unsigned short* W3arr=(unsigned short*)alloc(2*128*64*2);   // hi+lo
  int*   col    =(int*)  alloc((size_t)E*4);
  // reusable 256B-per-node slots
  float* A=(float*)alloc((size_t)M*256);   // (alias: uint tmp[E]) xs0 bf16[M,32]
  float* B=(float*)alloc((size_t)M*256);   // Y1 bf16[M,32] -> ts bf16[M,64]
  float* C=(float*)alloc((size_t)M*256);   // xs1 bf16[M,64] -> h3 bf16[M,64]
  float* D=(float*)alloc((size_t)M*256);   // Y2 bf16[M,64]
  unsigned* tmp=(unsigned*)A;              // E*4 bytes <= M*256 bytes
  (void)ws_size;(void)n_in;(void)out_size;

  hipMemsetAsync(bcnt,0,256*4,stream);
  coarsehist_kernel<<<512,256,0,stream>>>(dstp,bcnt,E,NB);
  binscan_kernel<<<1,256,0,stream>>>(bcnt,binoffs,bincur,NB,E);
  chunkscatter_kernel<<<(E+CHUNK-1)/CHUNK,256,0,stream>>>(srcp,dstp,bincur,tmp,E,NB);
  binsort_kernel<<<NB,512,0,stream>>>(tmp,binoffs,offs,deg,dinv,col,M,WSZ);
  wprep_kernel<<<(32*64+255)/256,256,0,stream>>>(W1,W1arr,1,21,64,32*64);
  wprep_kernel<<<(64*128+255)/256,256,0,stream>>>(W2,W2arr,2,64,128,64*128);
  wprep_kernel<<<(128*64+255)/256,256,0,stream>>>(W3,W3arr,4,128,64,128*64);

  // layer 1: xs0 bf16[M,32]; aggregate (GROUP=8 uint2, out bf16 Y1); MFMA GEMM 21->64 (bias+relu+dinv, bf16 xs1)
  scale_kernel<<<(M*8+255)/256,256,0,stream>>>(x,dinv,(uint2*)A,M);
  agg1_kernel<<<(M*8+255)/256,256,0,stream>>>((const uint2*)A,col,offs,deg,dinv,(uint2*)B,M);
  gemm1m_kernel<<<(M+63)/64,256,0,stream>>>((const unsigned short*)B,W1arr,b1,dinv,(unsigned short*)C,M);
  // layer 2+3 GEMMs fused: aggregate (GROUP=8 uint4, out bf16 Y2); Y2 -> (h2 in LDS) -> ts bf16
  agg2_kernel<<<(M*8+255)/256,256,0,stream>>>((const uint4*)C,col,offs,deg,dinv,(uint4*)D,M);
  gemm23_kernel<<<(M+63)/64,256,0,stream>>>((const unsigned short*)D,W2arr,W3arr,b2,dinv,(unsigned short*)B,M);
  // layer 3 aggregate (bias+relu, bf16 h3, GROUP=8 uint4)
  agg3_kernel<<<(M*8+255)/256,256,0,stream>>>((const uint4*)B,col,offs,deg,dinv,b3,(uint4*)C,M);
  // MLP head (bf16 input)
  mlp_kernel<<<(M+255)/256,256,0,stream>>>((const unsigned short*)C,Wl1,bl1,Wl2,bl2,(float*)d_out,M);
}